// Round 5
// baseline (325.246 us; speedup 1.0000x reference)
//
#include <hip/hip_runtime.h>
#include <hip/hip_bf16.h>
#include <math.h>
#include <stdint.h>

typedef unsigned short u16;
typedef __attribute__((ext_vector_type(8))) short bf8;   // 8 bf16 raw bits (4 VGPRs)
typedef __attribute__((ext_vector_type(4))) float f4;    // MFMA C/D frag

#define SC_LOG2E 0.09016844f   // 256^-0.5 * log2(e)

__device__ __forceinline__ float b2f(u16 u) {
    union { uint32_t i; float f; } v; v.i = ((uint32_t)u) << 16; return v.f;
}
__device__ __forceinline__ u16 f2b(float f) {
    union { float f; uint32_t i; } v; v.f = f;
    uint32_t r = (v.i + 0x7FFFu + ((v.i >> 16) & 1u)) >> 16;
    return (u16)r;
}

// ---------------------------------------------------------------------------
// Kernel 0: weight prep (f32 -> bf16, transposed).
// ---------------------------------------------------------------------------
__global__ __launch_bounds__(256) void prep_weights(
        const float* __restrict__ Wqkv, const float* __restrict__ Wgate,
        const float* __restrict__ Wproj,
        u16* __restrict__ WT_all, u16* __restrict__ WTp) {
    int e = blockIdx.x * 256 + threadIdx.x;
    if (e < 262144) {
        int n = e >> 8, k = e & 255;
        WT_all[e] = f2b((n < 768) ? Wqkv[k * 768 + n] : Wgate[k * 256 + (n - 768)]);
    } else {
        int e2 = e - 262144;
        int n = e2 >> 8, k = e2 & 255;
        WTp[e2] = f2b(Wproj[k * 256 + n]);
    }
}

// ---------------------------------------------------------------------------
// Kernel 1: fused GEMM  y = x @ [W_qkv | W_gate]  (M=16384, N=1024, K=256)
// ---------------------------------------------------------------------------
__global__ __launch_bounds__(512) void gemm_qkvz(
        const float* __restrict__ x, const u16* __restrict__ WT,
        const float* __restrict__ b_gate,
        u16* __restrict__ qo, u16* __restrict__ ko,
        u16* __restrict__ vT, u16* __restrict__ zo) {
    __shared__ u16 As[128][72];
    __shared__ u16 Bs[256][72];
    const int t = threadIdx.x;
    const int w = t >> 6, lane = t & 63, l15 = lane & 15, q4 = lane >> 4;
    const int m0 = blockIdx.x * 128;
    const int n0 = blockIdx.y * 256;

    f4 acc[16];
#pragma unroll
    for (int i = 0; i < 16; i++) acc[i] = (f4){0.f, 0.f, 0.f, 0.f};

    for (int kt = 0; kt < 4; ++kt) {
        __syncthreads();
#pragma unroll
        for (int p = 0; p < 2; p++) {   // A tile: 128x64, f32 -> bf16
            int r = p * 64 + (t >> 3), cg = (t & 7) * 8;
            const float* xs = &x[(m0 + r) * 256 + kt * 64 + cg];
            float4 f0 = *(const float4*)xs;
            float4 f1 = *(const float4*)(xs + 4);
            u16 tmp[8];
            tmp[0] = f2b(f0.x); tmp[1] = f2b(f0.y);
            tmp[2] = f2b(f0.z); tmp[3] = f2b(f0.w);
            tmp[4] = f2b(f1.x); tmp[5] = f2b(f1.y);
            tmp[6] = f2b(f1.z); tmp[7] = f2b(f1.w);
            *(bf8*)&As[r][cg] = *(bf8*)tmp;
        }
#pragma unroll
        for (int p = 0; p < 4; p++) {   // B tile: 256(n) x 64(k)
            int nr = p * 64 + (t >> 3), cg = (t & 7) * 8;
            *(bf8*)&Bs[nr][cg] = *(const bf8*)&WT[(n0 + nr) * 256 + kt * 64 + cg];
        }
        __syncthreads();
#pragma unroll
        for (int c = 0; c < 2; c++) {
            bf8 af = *(bf8*)&As[w * 16 + l15][c * 32 + q4 * 8];
#pragma unroll
            for (int nt = 0; nt < 16; nt++) {
                bf8 bf = *(bf8*)&Bs[nt * 16 + l15][c * 32 + q4 * 8];
                acc[nt] = __builtin_amdgcn_mfma_f32_16x16x32_bf16(af, bf, acc[nt], 0, 0, 0);
            }
        }
    }

    const int rb = m0 + w * 16 + q4 * 4;
    if (blockIdx.y == 0) {
#pragma unroll
        for (int nt = 0; nt < 16; nt++) {
            int col = nt * 16 + l15;
#pragma unroll
            for (int r = 0; r < 4; r++) qo[(rb + r) * 256 + col] = f2b(acc[nt][r]);
        }
    } else if (blockIdx.y == 1) {
#pragma unroll
        for (int nt = 0; nt < 16; nt++) {
            int col = nt * 16 + l15;
#pragma unroll
            for (int r = 0; r < 4; r++) ko[(rb + r) * 256 + col] = f2b(acc[nt][r]);
        }
    } else if (blockIdx.y == 2) {          // v transposed: vT[b][c][n]
        int bb = rb >> 12, nn = rb & 4095;
#pragma unroll
        for (int nt = 0; nt < 16; nt++) {
            int vc = nt * 16 + l15;
            ushort4 pk;
            pk.x = f2b(acc[nt][0]); pk.y = f2b(acc[nt][1]);
            pk.z = f2b(acc[nt][2]); pk.w = f2b(acc[nt][3]);
            *(ushort4*)&vT[(bb * 256 + vc) * 4096 + nn] = pk;
        }
    } else {                               // z = gelu_exact(y + b_gate)
#pragma unroll
        for (int nt = 0; nt < 16; nt++) {
            int gc = nt * 16 + l15;
            float bg = b_gate[gc];
#pragma unroll
            for (int r = 0; r < 4; r++) {
                float v = acc[nt][r] + bg;
                float g = 0.5f * v * (1.0f + erff(v * 0.70710678118654752f));
                zo[(rb + r) * 256 + gc] = f2b(g);
            }
        }
    }
}

// ---------------------------------------------------------------------------
// Kernel 2: depthwise 3x3 conv PE, sliding-window (3 loads/pixel).
// ---------------------------------------------------------------------------
__global__ __launch_bounds__(256) void conv_pe(
        const u16* __restrict__ q, const float* __restrict__ pw,
        const float* __restrict__ pb, u16* __restrict__ pe) {
    const int b = blockIdx.x >> 6, h = blockIdx.x & 63;
    const int c = threadIdx.x;
    float wgt[9];
#pragma unroll
    for (int i = 0; i < 9; i++) wgt[i] = pw[c * 9 + i];
    const float bias = pb[c];
    const u16* qb = q + b * (4096 * 256);
    u16* peb = pe + b * (4096 * 256);
    const bool vTop = h > 0, vBot = h < 63;
    const u16* rT = qb + (h - 1) * 64 * 256 + c;
    const u16* rM = qb + h * 64 * 256 + c;
    const u16* rB = qb + (h + 1) * 64 * 256 + c;

    float t0 = 0.f, t1, t2, m0v = 0.f, m1, m2, b0 = 0.f, b1, b2v;
    t1 = vTop ? b2f(rT[0]) : 0.f;
    m1 = b2f(rM[0]);
    b1 = vBot ? b2f(rB[0]) : 0.f;
    for (int w2 = 0; w2 < 64; ++w2) {
        if (w2 < 63) {
            int o = (w2 + 1) * 256;
            t2 = vTop ? b2f(rT[o]) : 0.f;
            m2 = b2f(rM[o]);
            b2v = vBot ? b2f(rB[o]) : 0.f;
        } else { t2 = 0.f; m2 = 0.f; b2v = 0.f; }
        float acc = bias
            + wgt[0] * t0 + wgt[1] * t1 + wgt[2] * t2
            + wgt[3] * m0v + wgt[4] * m1 + wgt[5] * m2
            + wgt[6] * b0 + wgt[7] * b1 + wgt[8] * b2v;
        peb[(h * 64 + w2) * 256 + c] = f2b(acc);
        t0 = t1; t1 = t2; m0v = m1; m1 = m2; b0 = b1; b1 = b2v;
    }
}

// ---------------------------------------------------------------------------
// Kernel 3: flash attention, no-max softmax, Q-tile 64.
// Grid 256 = 64 qtiles x 4 batches (b=bid&3 -> XCD-batch L2 affinity).
// 512 threads / 8 waves, 1 block/CU. NO min-waves in launch_bounds: r4's
// (512,2) capped VGPRs at 128 < the ~230 this kernel needs -> spills.
// Every wave holds ALL 64 Q-rows as B-operand regs (qf[4][8], 128 VGPRs).
// Per iter (128 keys): wave w owns keys [16w,16w+16) for QK (kf[8] batch,
// each reused 4x), P exchanged via dbuf LDS (ONE barrier/iter), then wave w
// owns v-cols [32w,32w+32) for PV (vf[8] hoisted batch, pf reused 2x).
// ---------------------------------------------------------------------------
__global__ __launch_bounds__(512) void attn(
        const u16* __restrict__ q, const u16* __restrict__ k,
        const u16* __restrict__ vT, const u16* __restrict__ pe,
        const u16* __restrict__ z, u16* __restrict__ u) {
    __shared__ u16 Ps[2][64][136];   // [buf][qrow][key], pad 8
    __shared__ float l_part[8][64];

    const int t = threadIdx.x;
    const int w = t >> 6, lane = t & 63, l15 = lane & 15, q4 = lane >> 4;
    const int b = blockIdx.x & 3, qt = blockIdx.x >> 2;
    const int m0 = b * 4096 + qt * 64;

    const u16* kb = k + (size_t)b * 4096 * 256;
    const u16* vb = vT + (size_t)b * 256 * 4096;

    // Q fragments (B-operand): all 64 rows of this block's Q-tile.
    bf8 qf[4][8];
#pragma unroll
    for (int qg = 0; qg < 4; qg++)
#pragma unroll
        for (int c = 0; c < 8; c++)
            qf[qg][c] = *(const bf8*)&q[(m0 + qg * 16 + l15) * 256 + c * 32 + q4 * 8];

    f4 O[4][2];
#pragma unroll
    for (int qg = 0; qg < 4; qg++) {
        O[qg][0] = (f4){0.f, 0.f, 0.f, 0.f};
        O[qg][1] = (f4){0.f, 0.f, 0.f, 0.f};
    }
    float lrow[4] = {0.f, 0.f, 0.f, 0.f};

    for (int kt = 0; kt < 32; ++kt) {
        const int k0 = kt * 128;
        // ---- hoisted K-fragment loads: wave's 16 keys x 256 d ----
        bf8 kf[8];
        const u16* krow = &kb[(k0 + w * 16 + l15) * 256 + q4 * 8];
#pragma unroll
        for (int c = 0; c < 8; c++) kf[c] = *(const bf8*)&krow[c * 32];

        // ---- QK: St[qg] = C[key 16][qrow 16], key=q4*4+r, qrow=l15 ----
        f4 St[4];
#pragma unroll
        for (int qg = 0; qg < 4; qg++) St[qg] = (f4){0.f, 0.f, 0.f, 0.f};
#pragma unroll
        for (int c = 0; c < 8; c++)
#pragma unroll
            for (int qg = 0; qg < 4; qg++)
                St[qg] = __builtin_amdgcn_mfma_f32_16x16x32_bf16(kf[c], qf[qg][c], St[qg], 0, 0, 0);

        // ---- P = exp(S*scale), bf16 -> dbuf LDS; l accumulated from exps ----
        u16 (*Pb)[136] = Ps[kt & 1];
#pragma unroll
        for (int qg = 0; qg < 4; qg++) {
            float e0 = exp2f(fminf(fmaxf(St[qg][0] * SC_LOG2E, -30.f), 30.f));
            float e1 = exp2f(fminf(fmaxf(St[qg][1] * SC_LOG2E, -30.f), 30.f));
            float e2 = exp2f(fminf(fmaxf(St[qg][2] * SC_LOG2E, -30.f), 30.f));
            float e3 = exp2f(fminf(fmaxf(St[qg][3] * SC_LOG2E, -30.f), 30.f));
            ushort4 pk;
            pk.x = f2b(e0); pk.y = f2b(e1); pk.z = f2b(e2); pk.w = f2b(e3);
            *(ushort4*)&Pb[qg * 16 + l15][w * 16 + q4 * 4] = pk;
            float s = (e0 + e1) + (e2 + e3);
            s += __shfl_xor(s, 16);
            s += __shfl_xor(s, 32);
            lrow[qg] += s;
        }
        __syncthreads();

        // ---- PV: wave w cols [32w,32w+32); vf[8] hoisted, pf reused 2x ----
        const int vc0 = w * 32;
        bf8 vf[8];
#pragma unroll
        for (int kg = 0; kg < 4; kg++) {
            vf[kg * 2]     = *(const bf8*)&vb[(vc0 + l15) * 4096 + k0 + kg * 32 + q4 * 8];
            vf[kg * 2 + 1] = *(const bf8*)&vb[(vc0 + 16 + l15) * 4096 + k0 + kg * 32 + q4 * 8];
        }
#pragma unroll
        for (int kg = 0; kg < 4; kg++) {
#pragma unroll
            for (int qg = 0; qg < 4; qg++) {
                bf8 pf = *(bf8*)&Pb[qg * 16 + l15][kg * 32 + q4 * 8];
                O[qg][0] = __builtin_amdgcn_mfma_f32_16x16x32_bf16(pf, vf[kg * 2], O[qg][0], 0, 0, 0);
                O[qg][1] = __builtin_amdgcn_mfma_f32_16x16x32_bf16(pf, vf[kg * 2 + 1], O[qg][1], 0, 0, 0);
            }
        }
    }

    if (q4 == 0) {
#pragma unroll
        for (int qg = 0; qg < 4; qg++) l_part[w][qg * 16 + l15] = lrow[qg];
    }
    __syncthreads();

    // ---- epilogue: u = (O/l + pe) * z -> bf16 ----
#pragma unroll
    for (int qg = 0; qg < 4; qg++) {
#pragma unroll
        for (int r = 0; r < 4; r++) {
            int row = qg * 16 + q4 * 4 + r;
            float lt = 0.f;
#pragma unroll
            for (int w2 = 0; w2 < 8; w2++) lt += l_part[w2][row];
            float linv = 1.0f / lt;
            int m = m0 + row;
#pragma unroll
            for (int vcg = 0; vcg < 2; vcg++) {
                int col = w * 32 + vcg * 16 + l15;
                float o = O[qg][vcg][r] * linv;
                float res = (o + b2f(pe[m * 256 + col])) * b2f(z[m * 256 + col]);
                u[m * 256 + col] = f2b(res);
            }
        }
    }
}

// ---------------------------------------------------------------------------
// Kernel 4: out = u @ W_proj   (M=16384, N=256, K=256). f32 output.
// ---------------------------------------------------------------------------
__global__ __launch_bounds__(256) void gemm_proj(
        const u16* __restrict__ u, const u16* __restrict__ WTp,
        float* __restrict__ out) {
    __shared__ u16 As[64][72];
    __shared__ u16 Bs[256][72];
    const int t = threadIdx.x;
    const int w = t >> 6, lane = t & 63, l15 = lane & 15, q4 = lane >> 4;
    const int m0 = blockIdx.x * 64;

    f4 acc[16];
#pragma unroll
    for (int i = 0; i < 16; i++) acc[i] = (f4){0.f, 0.f, 0.f, 0.f};

    for (int kt = 0; kt < 4; ++kt) {
        __syncthreads();
#pragma unroll
        for (int p = 0; p < 2; p++) {
            int r = p * 32 + (t >> 3), cg = (t & 7) * 8;
            *(bf8*)&As[r][cg] = *(const bf8*)&u[(m0 + r) * 256 + kt * 64 + cg];
        }
#pragma unroll
        for (int p = 0; p < 8; p++) {
            int nr = p * 32 + (t >> 3), cg = (t & 7) * 8;
            *(bf8*)&Bs[nr][cg] = *(const bf8*)&WTp[nr * 256 + kt * 64 + cg];
        }
        __syncthreads();
#pragma unroll
        for (int c = 0; c < 2; c++) {
            bf8 af = *(bf8*)&As[w * 16 + l15][c * 32 + q4 * 8];
#pragma unroll
            for (int nt = 0; nt < 16; nt++) {
                bf8 bf = *(bf8*)&Bs[nt * 16 + l15][c * 32 + q4 * 8];
                acc[nt] = __builtin_amdgcn_mfma_f32_16x16x32_bf16(af, bf, acc[nt], 0, 0, 0);
            }
        }
    }
    const int rb = m0 + w * 16 + q4 * 4;
#pragma unroll
    for (int nt = 0; nt < 16; nt++) {
        int col = nt * 16 + l15;
#pragma unroll
        for (int r = 0; r < 4; r++) out[(rb + r) * 256 + col] = acc[nt][r];
    }
}

// ---------------------------------------------------------------------------
extern "C" void kernel_launch(void* const* d_in, const int* in_sizes, int n_in,
                              void* d_out, int out_size, void* d_ws, size_t ws_size,
                              hipStream_t stream) {
    (void)in_sizes; (void)n_in; (void)out_size; (void)ws_size;
    const float* x      = (const float*)d_in[0];
    const float* Wqkv   = (const float*)d_in[1];
    const float* Wgate  = (const float*)d_in[2];
    const float* bgate  = (const float*)d_in[3];
    const float* Wproj  = (const float*)d_in[4];
    const float* pw     = (const float*)d_in[5];
    const float* pb     = (const float*)d_in[6];
    float* out = (float*)d_out;

    char* ws = (char*)d_ws;
    u16* WT_all = (u16*)(ws);                   // 524288 B
    u16* WTp    = (u16*)(ws + 524288);          // 131072 B
    u16* q      = (u16*)(ws + 655360);          // 8388608
    u16* k      = (u16*)(ws + 9043968);         // 8388608
    u16* vT     = (u16*)(ws + 17432576);        // 8388608
    u16* z      = (u16*)(ws + 25821184);        // 8388608
    u16* pe     = (u16*)(ws + 34209792);        // 8388608
    u16* u      = (u16*)(ws + 42598400);        // 8388608

    prep_weights<<<1280, 256, 0, stream>>>(Wqkv, Wgate, Wproj, WT_all, WTp);
    gemm_qkvz<<<dim3(128, 4), 512, 0, stream>>>(x, WT_all, bgate, q, k, vT, z);
    conv_pe<<<256, 256, 0, stream>>>(q, pw, pb, pe);
    attn<<<256, 512, 0, stream>>>(q, k, vT, pe, z, u);
    gemm_proj<<<256, 256, 0, stream>>>(u, WTp, out);
}